// Round 1
// baseline (1031.126 us; speedup 1.0000x reference)
//
#include <hip/hip_runtime.h>

#define NN 100000
#define NE 1600000
#define FI 32
#define FH 30
#define NG 512

// order-preserving encode for float atomicMax on unsigned
__device__ inline unsigned encf(float f) {
    unsigned u = __float_as_uint(f);
    return (u & 0x80000000u) ? ~u : (u | 0x80000000u);
}
__device__ inline float decf(unsigned u) {
    unsigned b = (u & 0x80000000u) ? (u & 0x7FFFFFFFu) : ~u;
    return __uint_as_float(b);
}

// layer-1 aggregation: 32 lanes per edge, feature f = tid&31 (coalesced 128B per half-wave)
__global__ __launch_bounds__(256) void k_agg1(
    const int* __restrict__ src, const int* __restrict__ dst,
    const float* __restrict__ x, float* __restrict__ s1, float* __restrict__ cnt)
{
    int tid = blockIdx.x * 256 + threadIdx.x;
    int e = tid >> 5;
    int f = tid & 31;
    if (e >= NE) return;
    int s = src[e], d = dst[e];
    atomicAdd(&s1[(long long)d * FI + f], x[(long long)s * FI + f]);
    if (f == 0) atomicAdd(&cnt[d], 1.0f);
}

// layer-2 aggregation: 32 lanes per edge, 30 active
__global__ __launch_bounds__(256) void k_agg2(
    const int* __restrict__ src, const int* __restrict__ dst,
    const float* __restrict__ h1, float* __restrict__ s2)
{
    int tid = blockIdx.x * 256 + threadIdx.x;
    int e = tid >> 5;
    int f = tid & 31;
    if (e >= NE || f >= FH) return;
    int s = src[e], d = dst[e];
    atomicAdd(&s2[(long long)d * FH + f], h1[(long long)s * FH + f]);
}

// node transform layer 1: h1 = bn(relu(agg@Wl^T + bl + x@Wr^T))
__global__ __launch_bounds__(256) void k_t1(
    const float* __restrict__ x, const float* __restrict__ s1, const float* __restrict__ cnt,
    const float* __restrict__ Wl, const float* __restrict__ bl, const float* __restrict__ Wr,
    const float* __restrict__ g, const float* __restrict__ b,
    const float* __restrict__ m, const float* __restrict__ v,
    float* __restrict__ h1)
{
    __shared__ float sWl[FH * FI], sWr[FH * FI], sBias[FH], sScale[FH], sShift[FH];
    for (int i = threadIdx.x; i < FH * FI; i += 256) { sWl[i] = Wl[i]; sWr[i] = Wr[i]; }
    if (threadIdx.x < FH) {
        int j = threadIdx.x;
        float sc = g[j] * rsqrtf(v[j] + 1e-5f);
        sBias[j] = bl[j];
        sScale[j] = sc;
        sShift[j] = b[j] - m[j] * sc;
    }
    __syncthreads();
    int n = blockIdx.x * 256 + threadIdx.x;
    if (n >= NN) return;
    float xr[FI], ar[FI];
    float inv = 1.0f / fmaxf(cnt[n], 1.0f);
    #pragma unroll
    for (int k = 0; k < FI; k += 4) {
        float4 xv = *(const float4*)(x + (long long)n * FI + k);
        float4 sv = *(const float4*)(s1 + (long long)n * FI + k);
        xr[k] = xv.x; xr[k+1] = xv.y; xr[k+2] = xv.z; xr[k+3] = xv.w;
        ar[k] = sv.x * inv; ar[k+1] = sv.y * inv; ar[k+2] = sv.z * inv; ar[k+3] = sv.w * inv;
    }
    for (int j = 0; j < FH; ++j) {
        float acc = sBias[j];
        #pragma unroll
        for (int k = 0; k < FI; ++k)
            acc += ar[k] * sWl[j * FI + k] + xr[k] * sWr[j * FI + k];
        acc = fmaxf(acc, 0.0f);
        h1[(long long)n * FH + j] = acc * sScale[j] + sShift[j];
    }
}

// node transform layer 2 fused with dual segment pooling (sum + max)
__global__ __launch_bounds__(256) void k_t2(
    const float* __restrict__ h1, const float* __restrict__ s2, const float* __restrict__ cnt,
    const int* __restrict__ batch,
    const float* __restrict__ Wl, const float* __restrict__ bl, const float* __restrict__ Wr,
    const float* __restrict__ g, const float* __restrict__ b,
    const float* __restrict__ m, const float* __restrict__ v,
    float* __restrict__ gsum, unsigned* __restrict__ gmax, float* __restrict__ gcnt)
{
    __shared__ float sWl[FH * FH], sWr[FH * FH], sBias[FH], sScale[FH], sShift[FH];
    for (int i = threadIdx.x; i < FH * FH; i += 256) { sWl[i] = Wl[i]; sWr[i] = Wr[i]; }
    if (threadIdx.x < FH) {
        int j = threadIdx.x;
        float sc = g[j] * rsqrtf(v[j] + 1e-5f);
        sBias[j] = bl[j];
        sScale[j] = sc;
        sShift[j] = b[j] - m[j] * sc;
    }
    __syncthreads();
    int n = blockIdx.x * 256 + threadIdx.x;
    if (n >= NN) return;
    float hr[FH], ar[FH];
    float inv = 1.0f / fmaxf(cnt[n], 1.0f);
    #pragma unroll
    for (int k = 0; k < FH; ++k) {
        hr[k] = h1[(long long)n * FH + k];
        ar[k] = s2[(long long)n * FH + k] * inv;
    }
    int bg = batch[n];
    for (int j = 0; j < FH; ++j) {
        float acc = sBias[j];
        #pragma unroll
        for (int k = 0; k < FH; ++k)
            acc += ar[k] * sWl[j * FH + k] + hr[k] * sWr[j * FH + k];
        acc = fmaxf(acc, 0.0f);
        float val = acc * sScale[j] + sShift[j];
        atomicAdd(&gsum[bg * FH + j], val);
        atomicMax(&gmax[bg * FH + j], encf(val));
    }
    atomicAdd(&gcnt[bg], 1.0f);
}

// final MLP over [G,60] -> 10 -> 1 -> sigmoid
__global__ __launch_bounds__(256) void k_mlp(
    const float* __restrict__ gsum, const unsigned* __restrict__ gmax,
    const float* __restrict__ gcnt,
    const float* __restrict__ W1, const float* __restrict__ bb1,
    const float* __restrict__ W2, const float* __restrict__ bb2,
    float* __restrict__ out)
{
    int gi = blockIdx.x * 256 + threadIdx.x;
    if (gi >= NG) return;
    float c = gcnt[gi];
    float invc = 1.0f / fmaxf(c, 1.0f);
    float z[2 * FH];
    for (int j = 0; j < FH; ++j) z[j] = (c > 0.0f) ? decf(gmax[gi * FH + j]) : 0.0f;
    for (int j = 0; j < FH; ++j) z[FH + j] = gsum[gi * FH + j] * invc;
    float o = bb2[0];
    for (int j = 0; j < 10; ++j) {
        float t = bb1[j];
        for (int k = 0; k < 2 * FH; ++k) t += z[k] * W1[j * 2 * FH + k];
        t = fmaxf(t, 0.0f);
        o += t * W2[j];
    }
    out[gi] = 1.0f / (1.0f + expf(-o));
}

extern "C" void kernel_launch(void* const* d_in, const int* in_sizes, int n_in,
                              void* d_out, int out_size, void* d_ws, size_t ws_size,
                              hipStream_t stream)
{
    const float* x   = (const float*)d_in[0];
    const int*   ei  = (const int*)d_in[1];
    const int*   bat = (const int*)d_in[2];
    const float* Wl1 = (const float*)d_in[3];
    const float* bl1 = (const float*)d_in[4];
    const float* Wr1 = (const float*)d_in[5];
    const float* Wl2 = (const float*)d_in[6];
    const float* bl2 = (const float*)d_in[7];
    const float* Wr2 = (const float*)d_in[8];
    const float* g1  = (const float*)d_in[9];
    const float* b1  = (const float*)d_in[10];
    const float* m1  = (const float*)d_in[11];
    const float* v1  = (const float*)d_in[12];
    const float* g2  = (const float*)d_in[13];
    const float* b2  = (const float*)d_in[14];
    const float* m2  = (const float*)d_in[15];
    const float* v2  = (const float*)d_in[16];
    const float* W1  = (const float*)d_in[17];
    const float* bb1 = (const float*)d_in[18];
    const float* W2  = (const float*)d_in[19];
    const float* bb2 = (const float*)d_in[20];

    const int* src = ei;
    const int* dst = ei + NE;

    float* ws = (float*)d_ws;
    float*    cnt  = ws;                                   // NN
    float*    s1   = cnt + NN;                             // NN*FI
    float*    s2   = s1 + (size_t)NN * FI;                 // NN*FH
    float*    gsum = s2 + (size_t)NN * FH;                 // NG*FH
    unsigned* gmax = (unsigned*)(gsum + NG * FH);          // NG*FH (0 == below all encoded floats)
    float*    gcnt = (float*)(gmax + NG * FH);             // NG
    float*    h1   = gcnt + NG;                            // NN*FH (fully overwritten, no init)

    size_t zeroFloats = (size_t)NN * (1 + FI + FH) + (size_t)NG * (2 * FH + 1);
    hipMemsetAsync(d_ws, 0, zeroFloats * sizeof(float), stream);

    int aggBlocks = (NE * 32) / 256;  // 200000
    k_agg1<<<aggBlocks, 256, 0, stream>>>(src, dst, x, s1, cnt);
    k_t1<<<(NN + 255) / 256, 256, 0, stream>>>(x, s1, cnt, Wl1, bl1, Wr1, g1, b1, m1, v1, h1);
    k_agg2<<<aggBlocks, 256, 0, stream>>>(src, dst, h1, s2);
    k_t2<<<(NN + 255) / 256, 256, 0, stream>>>(h1, s2, cnt, bat, Wl2, bl2, Wr2, g2, b2, m2, v2,
                                               gsum, gmax, gcnt);
    k_mlp<<<(NG + 255) / 256, 256, 0, stream>>>(gsum, gmax, gcnt, W1, bb1, W2, bb2, (float*)d_out);
}

// Round 2
// 850.675 us; speedup vs baseline: 1.2121x; 1.2121x over previous
//
#include <hip/hip_runtime.h>

#define NN 100000
#define NE 1600000
#define FI 32
#define FH 30
#define NG 512
#define NB1 391   // ceil(NN/256)

// ---------- CSR build ----------
__global__ __launch_bounds__(256) void k_hist(const int* __restrict__ dst, int* __restrict__ deg)
{
    int e = blockIdx.x * 256 + threadIdx.x;
    if (e < NE) atomicAdd(&deg[dst[e]], 1);
}

__global__ __launch_bounds__(256) void k_scan1(const int* __restrict__ deg,
                                               int* __restrict__ rowstart, int* __restrict__ btot)
{
    __shared__ int tmp[256];
    int i = blockIdx.x * 256 + threadIdx.x;
    int v = (i < NN) ? deg[i] : 0;
    tmp[threadIdx.x] = v;
    __syncthreads();
    for (int off = 1; off < 256; off <<= 1) {
        int t = (threadIdx.x >= off) ? tmp[threadIdx.x - off] : 0;
        __syncthreads();
        tmp[threadIdx.x] += t;
        __syncthreads();
    }
    if (i < NN) rowstart[i] = tmp[threadIdx.x] - v;   // exclusive within block
    if (threadIdx.x == 255) btot[blockIdx.x] = tmp[255];
}

__global__ __launch_bounds__(512) void k_scan2(const int* __restrict__ btot, int* __restrict__ boff)
{
    __shared__ int tmp[512];
    int tid = threadIdx.x;
    int v = (tid < NB1) ? btot[tid] : 0;
    tmp[tid] = v;
    __syncthreads();
    for (int off = 1; off < 512; off <<= 1) {
        int t = (tid >= off) ? tmp[tid - off] : 0;
        __syncthreads();
        tmp[tid] += t;
        __syncthreads();
    }
    if (tid < NB1) boff[tid] = tmp[tid] - v;          // exclusive block offsets
}

__global__ __launch_bounds__(256) void k_scan3(int* __restrict__ rowstart,
                                               const int* __restrict__ boff, int* __restrict__ pos)
{
    int i = blockIdx.x * 256 + threadIdx.x;
    if (i < NN) {
        int r = rowstart[i] + boff[blockIdx.x];
        rowstart[i] = r;
        pos[i] = r;
        if (i == 0) rowstart[NN] = NE;
    }
}

__global__ __launch_bounds__(256) void k_scatter(const int* __restrict__ src, const int* __restrict__ dst,
                                                 int* __restrict__ pos, int* __restrict__ col)
{
    int e = blockIdx.x * 256 + threadIdx.x;
    if (e < NE) {
        int p = atomicAdd(&pos[dst[e]], 1);
        col[p] = src[e];
    }
}

// ---------- CSR mean aggregation: one wave per node, 2 edges per iter ----------
template <int F>
__global__ __launch_bounds__(256) void k_aggcsr(const int* __restrict__ rowstart,
                                                const int* __restrict__ col,
                                                const float* __restrict__ hin,
                                                float* __restrict__ aggout)
{
    int tid = blockIdx.x * 256 + threadIdx.x;
    int n = tid >> 6;
    if (n >= NN) return;
    int lane = threadIdx.x & 63;
    int f = lane & 31;
    int half = lane >> 5;
    int rs = rowstart[n], re = rowstart[n + 1];
    float acc = 0.0f;
    if (f < F) {
        for (int e = rs + half; e < re; e += 2)
            acc += hin[(long long)col[e] * F + f];
    }
    acc += __shfl_xor(acc, 32);
    if (half == 0 && f < F) {
        float inv = (re > rs) ? 1.0f / (float)(re - rs) : 0.0f;
        aggout[(long long)n * F + f] = acc * inv;
    }
}

// ---------- layer-1 node transform: h1 = bn(relu(agg@Wl^T + bl + x@Wr^T)) ----------
__global__ __launch_bounds__(256) void k_t1(
    const float* __restrict__ x, const float* __restrict__ agg,
    const float* __restrict__ Wl, const float* __restrict__ bl, const float* __restrict__ Wr,
    const float* __restrict__ g, const float* __restrict__ b,
    const float* __restrict__ m, const float* __restrict__ v,
    float* __restrict__ h1)
{
    __shared__ float sWl[FH * FI], sWr[FH * FI], sBias[FH], sScale[FH], sShift[FH];
    for (int i = threadIdx.x; i < FH * FI; i += 256) { sWl[i] = Wl[i]; sWr[i] = Wr[i]; }
    if (threadIdx.x < FH) {
        int j = threadIdx.x;
        float sc = g[j] * rsqrtf(v[j] + 1e-5f);
        sBias[j] = bl[j];
        sScale[j] = sc;
        sShift[j] = b[j] - m[j] * sc;
    }
    __syncthreads();
    int n = blockIdx.x * 256 + threadIdx.x;
    if (n >= NN) return;
    float xr[FI], ar[FI];
    #pragma unroll
    for (int k = 0; k < FI; k += 4) {
        float4 xv = *(const float4*)(x + (long long)n * FI + k);
        float4 av = *(const float4*)(agg + (long long)n * FI + k);
        xr[k] = xv.x; xr[k+1] = xv.y; xr[k+2] = xv.z; xr[k+3] = xv.w;
        ar[k] = av.x; ar[k+1] = av.y; ar[k+2] = av.z; ar[k+3] = av.w;
    }
    for (int j = 0; j < FH; ++j) {
        float acc = sBias[j];
        #pragma unroll
        for (int k = 0; k < FI; ++k)
            acc += ar[k] * sWl[j * FI + k] + xr[k] * sWr[j * FI + k];
        acc = fmaxf(acc, 0.0f);
        h1[(long long)n * FH + j] = acc * sScale[j] + sShift[j];
    }
}

// ---------- layer-2 transform + per-graph pooling + MLP, one block per graph ----------
__global__ __launch_bounds__(256) void k_t2g(
    const float* __restrict__ h1, const float* __restrict__ agg,
    const int* __restrict__ batch,
    const float* __restrict__ Wl, const float* __restrict__ bl, const float* __restrict__ Wr,
    const float* __restrict__ g, const float* __restrict__ b,
    const float* __restrict__ m, const float* __restrict__ v,
    const float* __restrict__ W1, const float* __restrict__ bb1,
    const float* __restrict__ W2, const float* __restrict__ bb2,
    float* __restrict__ out)
{
    __shared__ float sWl[FH * FH], sWr[FH * FH], sBias[FH], sScale[FH], sShift[FH];
    __shared__ float sS[4][FH], sM[4][FH], sz[2 * FH], st[10];
    int tid = threadIdx.x;
    for (int i = tid; i < FH * FH; i += 256) { sWl[i] = Wl[i]; sWr[i] = Wr[i]; }
    if (tid < FH) {
        float sc = g[tid] * rsqrtf(v[tid] + 1e-5f);
        sBias[tid] = bl[tid];
        sScale[tid] = sc;
        sShift[tid] = b[tid] - m[tid] * sc;
    }
    __syncthreads();
    int gi = blockIdx.x;
    // batch is sorted: binary search [start,end) of this graph
    int lo = 0, hi = NN;
    while (lo < hi) { int mid = (lo + hi) >> 1; if (batch[mid] < gi) lo = mid + 1; else hi = mid; }
    int start = lo;
    hi = NN;
    while (lo < hi) { int mid = (lo + hi) >> 1; if (batch[mid] <= gi) lo = mid + 1; else hi = mid; }
    int end = lo;

    float sum[FH], mx[FH];
    #pragma unroll
    for (int j = 0; j < FH; ++j) { sum[j] = 0.0f; mx[j] = -INFINITY; }

    for (int n = start + tid; n < end; n += 256) {
        float hr[FH], ar[FH];
        #pragma unroll
        for (int k = 0; k < FH; ++k) {
            hr[k] = h1[(long long)n * FH + k];
            ar[k] = agg[(long long)n * FH + k];
        }
        #pragma unroll
        for (int j = 0; j < FH; ++j) {
            float acc = sBias[j];
            #pragma unroll
            for (int k = 0; k < FH; ++k)
                acc += ar[k] * sWl[j * FH + k] + hr[k] * sWr[j * FH + k];
            acc = fmaxf(acc, 0.0f);
            float val = acc * sScale[j] + sShift[j];
            sum[j] += val;
            mx[j] = fmaxf(mx[j], val);
        }
    }

    int lane = tid & 63, wid = tid >> 6;
    #pragma unroll
    for (int j = 0; j < FH; ++j) {
        float s = sum[j], mm = mx[j];
        for (int off = 32; off >= 1; off >>= 1) {
            s += __shfl_xor(s, off);
            mm = fmaxf(mm, __shfl_xor(mm, off));
        }
        if (lane == 0) { sS[wid][j] = s; sM[wid][j] = mm; }
    }
    __syncthreads();
    if (tid < FH) {
        float s = 0.0f, mm = -INFINITY;
        #pragma unroll
        for (int w = 0; w < 4; ++w) { s += sS[w][tid]; mm = fmaxf(mm, sM[w][tid]); }
        int c = end - start;
        sz[tid]      = (c > 0) ? mm : 0.0f;            // segment_max with isfinite->0
        sz[FH + tid] = (c > 0) ? s / (float)c : 0.0f;  // segment mean
    }
    __syncthreads();
    if (tid < 10) {
        float t = bb1[tid];
        for (int k = 0; k < 2 * FH; ++k) t += sz[k] * W1[tid * 2 * FH + k];
        st[tid] = fmaxf(t, 0.0f);
    }
    __syncthreads();
    if (tid == 0) {
        float o = bb2[0];
        for (int j = 0; j < 10; ++j) o += st[j] * W2[j];
        out[gi] = 1.0f / (1.0f + expf(-o));
    }
}

extern "C" void kernel_launch(void* const* d_in, const int* in_sizes, int n_in,
                              void* d_out, int out_size, void* d_ws, size_t ws_size,
                              hipStream_t stream)
{
    const float* x   = (const float*)d_in[0];
    const int*   ei  = (const int*)d_in[1];
    const int*   bat = (const int*)d_in[2];
    const float* Wl1 = (const float*)d_in[3];
    const float* bl1 = (const float*)d_in[4];
    const float* Wr1 = (const float*)d_in[5];
    const float* Wl2 = (const float*)d_in[6];
    const float* bl2 = (const float*)d_in[7];
    const float* Wr2 = (const float*)d_in[8];
    const float* g1  = (const float*)d_in[9];
    const float* b1  = (const float*)d_in[10];
    const float* m1  = (const float*)d_in[11];
    const float* v1  = (const float*)d_in[12];
    const float* g2  = (const float*)d_in[13];
    const float* b2  = (const float*)d_in[14];
    const float* m2  = (const float*)d_in[15];
    const float* v2  = (const float*)d_in[16];
    const float* W1  = (const float*)d_in[17];
    const float* bb1 = (const float*)d_in[18];
    const float* W2  = (const float*)d_in[19];
    const float* bb2 = (const float*)d_in[20];

    const int* src = ei;
    const int* dst = ei + NE;

    // workspace layout (all 4B elems; offsets keep 16B alignment for float4 users)
    int* wsi = (int*)d_ws;
    int* deg      = wsi;                    // NN
    int* rowstart = deg + NN;               // NN+1 (padded to NN+4)
    int* btot     = rowstart + NN + 4;      // 512
    int* boff     = btot + 512;             // 512
    int* pos      = boff + 512;             // NN
    int* col      = pos + NN;               // NE
    float* aggbuf = (float*)(col + NE);     // NN*FI (layer1), reused as NN*FH (layer2)
    float* h1     = aggbuf + (size_t)NN * FI; // NN*FH

    hipMemsetAsync(deg, 0, NN * sizeof(int), stream);

    int eb = (NE + 255) / 256;
    k_hist   <<<eb, 256, 0, stream>>>(dst, deg);
    k_scan1  <<<NB1, 256, 0, stream>>>(deg, rowstart, btot);
    k_scan2  <<<1, 512, 0, stream>>>(btot, boff);
    k_scan3  <<<NB1, 256, 0, stream>>>(rowstart, boff, pos);
    k_scatter<<<eb, 256, 0, stream>>>(src, dst, pos, col);

    int ab = (NN * 64 + 255) / 256;  // one wave per node
    k_aggcsr<FI><<<ab, 256, 0, stream>>>(rowstart, col, x, aggbuf);
    k_t1<<<NB1, 256, 0, stream>>>(x, aggbuf, Wl1, bl1, Wr1, g1, b1, m1, v1, h1);
    k_aggcsr<FH><<<ab, 256, 0, stream>>>(rowstart, col, h1, aggbuf);
    k_t2g<<<NG, 256, 0, stream>>>(h1, aggbuf, bat, Wl2, bl2, Wr2, g2, b2, m2, v2,
                                  W1, bb1, W2, bb2, (float*)d_out);
}

// Round 3
// 436.096 us; speedup vs baseline: 2.3644x; 1.9507x over previous
//
#include <hip/hip_runtime.h>

#define NN 100000
#define NE 1600000
#define FI 32
#define FH 30
#define NG 512
#define NB1 391   // ceil(NN/256)

// ---------- CSR build ----------
__global__ __launch_bounds__(256) void k_hist(const int* __restrict__ dst, int* __restrict__ deg)
{
    int e = blockIdx.x * 256 + threadIdx.x;
    if (e < NE) atomicAdd(&deg[dst[e]], 1);
}

__global__ __launch_bounds__(256) void k_scan1(const int* __restrict__ deg,
                                               int* __restrict__ rowstart, int* __restrict__ btot)
{
    __shared__ int tmp[256];
    int i = blockIdx.x * 256 + threadIdx.x;
    int v = (i < NN) ? deg[i] : 0;
    tmp[threadIdx.x] = v;
    __syncthreads();
    for (int off = 1; off < 256; off <<= 1) {
        int t = (threadIdx.x >= off) ? tmp[threadIdx.x - off] : 0;
        __syncthreads();
        tmp[threadIdx.x] += t;
        __syncthreads();
    }
    if (i < NN) rowstart[i] = tmp[threadIdx.x] - v;   // exclusive within block
    if (threadIdx.x == 255) btot[blockIdx.x] = tmp[255];
}

__global__ __launch_bounds__(512) void k_scan2(const int* __restrict__ btot, int* __restrict__ boff)
{
    __shared__ int tmp[512];
    int tid = threadIdx.x;
    int v = (tid < NB1) ? btot[tid] : 0;
    tmp[tid] = v;
    __syncthreads();
    for (int off = 1; off < 512; off <<= 1) {
        int t = (tid >= off) ? tmp[tid - off] : 0;
        __syncthreads();
        tmp[tid] += t;
        __syncthreads();
    }
    if (tid < NB1) boff[tid] = tmp[tid] - v;          // exclusive block offsets
}

__global__ __launch_bounds__(256) void k_scan3(int* __restrict__ rowstart,
                                               const int* __restrict__ boff, int* __restrict__ pos)
{
    int i = blockIdx.x * 256 + threadIdx.x;
    if (i < NN) {
        int r = rowstart[i] + boff[blockIdx.x];
        rowstart[i] = r;
        pos[i] = r;
        if (i == 0) rowstart[NN] = NE;
    }
}

__global__ __launch_bounds__(256) void k_scatter(const int* __restrict__ src, const int* __restrict__ dst,
                                                 int* __restrict__ pos, int* __restrict__ col)
{
    int e = blockIdx.x * 256 + threadIdx.x;
    if (e < NE) {
        int p = atomicAdd(&pos[dst[e]], 1);
        col[p] = src[e];
    }
}

// ---------- CSR mean aggregation: one wave per node, 2 edges per iter ----------
template <int F>
__global__ __launch_bounds__(256) void k_aggcsr(const int* __restrict__ rowstart,
                                                const int* __restrict__ col,
                                                const float* __restrict__ hin,
                                                float* __restrict__ aggout)
{
    int tid = blockIdx.x * 256 + threadIdx.x;
    int n = tid >> 6;
    if (n >= NN) return;
    int lane = threadIdx.x & 63;
    int f = lane & 31;
    int half = lane >> 5;
    int rs = rowstart[n], re = rowstart[n + 1];
    float acc = 0.0f;
    if (f < F) {
        for (int e = rs + half; e < re; e += 2)
            acc += hin[(long long)col[e] * F + f];
    }
    acc += __shfl_xor(acc, 32);
    if (half == 0 && f < F) {
        float inv = (re > rs) ? 1.0f / (float)(re - rs) : 0.0f;
        aggout[(long long)n * F + f] = acc * inv;
    }
}

// ---------- node transform: h_out = bn(relu(agg@Wl^T + bl + h_in@Wr^T)) ----------
template <int F>  // input feature count; output always FH
__global__ __launch_bounds__(256) void k_trans(
    const float* __restrict__ hin, const float* __restrict__ agg,
    const float* __restrict__ Wl, const float* __restrict__ bl, const float* __restrict__ Wr,
    const float* __restrict__ g, const float* __restrict__ b,
    const float* __restrict__ m, const float* __restrict__ v,
    float* __restrict__ hout)
{
    __shared__ float sWl[FH * F], sWr[FH * F], sBias[FH], sScale[FH], sShift[FH];
    for (int i = threadIdx.x; i < FH * F; i += 256) { sWl[i] = Wl[i]; sWr[i] = Wr[i]; }
    if (threadIdx.x < FH) {
        int j = threadIdx.x;
        float sc = g[j] * rsqrtf(v[j] + 1e-5f);
        sBias[j] = bl[j];
        sScale[j] = sc;
        sShift[j] = b[j] - m[j] * sc;
    }
    __syncthreads();
    int n = blockIdx.x * 256 + threadIdx.x;
    if (n >= NN) return;
    float xr[F], ar[F];
    #pragma unroll
    for (int k = 0; k < F; ++k) {
        xr[k] = hin[(long long)n * F + k];
        ar[k] = agg[(long long)n * F + k];
    }
    for (int j = 0; j < FH; ++j) {
        float acc = sBias[j];
        #pragma unroll
        for (int k = 0; k < F; ++k)
            acc += ar[k] * sWl[j * F + k] + xr[k] * sWr[j * F + k];
        acc = fmaxf(acc, 0.0f);
        hout[(long long)n * FH + j] = acc * sScale[j] + sShift[j];
    }
}

// ---------- per-graph dual pooling + MLP: one block per graph, feature-parallel ----------
__global__ __launch_bounds__(256) void k_pool(
    const float* __restrict__ h2, const int* __restrict__ batch,
    const float* __restrict__ W1, const float* __restrict__ bb1,
    const float* __restrict__ W2, const float* __restrict__ bb2,
    float* __restrict__ out)
{
    __shared__ float sS[8][FH], sM[8][FH], sz[2 * FH], st[10];
    int tid = threadIdx.x;
    int gi = blockIdx.x;
    // batch is sorted: binary search [start,end) of this graph
    int lo = 0, hi = NN;
    while (lo < hi) { int mid = (lo + hi) >> 1; if (batch[mid] < gi) lo = mid + 1; else hi = mid; }
    int start = lo;
    hi = NN;
    while (lo < hi) { int mid = (lo + hi) >> 1; if (batch[mid] <= gi) lo = mid + 1; else hi = mid; }
    int end = lo;

    int f = tid & 31;      // feature (active if < FH)
    int ng = tid >> 5;     // node group 0..7
    float sum = 0.0f, mx = -INFINITY;
    if (f < FH) {
        for (int n = start + ng; n < end; n += 8) {
            float val = h2[(long long)n * FH + f];
            sum += val;
            mx = fmaxf(mx, val);
        }
        sS[ng][f] = sum;
        sM[ng][f] = mx;
    }
    __syncthreads();
    if (tid < FH) {
        float s = 0.0f, mm = -INFINITY;
        #pragma unroll
        for (int w = 0; w < 8; ++w) { s += sS[w][tid]; mm = fmaxf(mm, sM[w][tid]); }
        int c = end - start;
        sz[tid]      = (c > 0) ? mm : 0.0f;            // segment_max (empty -> 0)
        sz[FH + tid] = (c > 0) ? s / (float)c : 0.0f;  // segment mean
    }
    __syncthreads();
    if (tid < 10) {
        float t = bb1[tid];
        for (int k = 0; k < 2 * FH; ++k) t += sz[k] * W1[tid * 2 * FH + k];
        st[tid] = fmaxf(t, 0.0f);
    }
    __syncthreads();
    if (tid == 0) {
        float o = bb2[0];
        for (int j = 0; j < 10; ++j) o += st[j] * W2[j];
        out[gi] = 1.0f / (1.0f + expf(-o));
    }
}

extern "C" void kernel_launch(void* const* d_in, const int* in_sizes, int n_in,
                              void* d_out, int out_size, void* d_ws, size_t ws_size,
                              hipStream_t stream)
{
    const float* x   = (const float*)d_in[0];
    const int*   ei  = (const int*)d_in[1];
    const int*   bat = (const int*)d_in[2];
    const float* Wl1 = (const float*)d_in[3];
    const float* bl1 = (const float*)d_in[4];
    const float* Wr1 = (const float*)d_in[5];
    const float* Wl2 = (const float*)d_in[6];
    const float* bl2 = (const float*)d_in[7];
    const float* Wr2 = (const float*)d_in[8];
    const float* g1  = (const float*)d_in[9];
    const float* b1  = (const float*)d_in[10];
    const float* m1  = (const float*)d_in[11];
    const float* v1  = (const float*)d_in[12];
    const float* g2  = (const float*)d_in[13];
    const float* b2  = (const float*)d_in[14];
    const float* m2  = (const float*)d_in[15];
    const float* v2  = (const float*)d_in[16];
    const float* W1  = (const float*)d_in[17];
    const float* bb1 = (const float*)d_in[18];
    const float* W2  = (const float*)d_in[19];
    const float* bb2 = (const float*)d_in[20];

    const int* src = ei;
    const int* dst = ei + NE;

    // workspace layout (all 4B elems)
    int* wsi = (int*)d_ws;
    int* deg      = wsi;                      // NN
    int* rowstart = deg + NN;                 // NN+1 (padded to NN+4)
    int* btot     = rowstart + NN + 4;        // 512
    int* boff     = btot + 512;               // 512
    int* pos      = boff + 512;               // NN
    int* col      = pos + NN;                 // NE
    float* aggbuf = (float*)(col + NE);       // NN*FI (layer1), reused as NN*FH (layer2)
    float* h1     = aggbuf + (size_t)NN * FI; // NN*FH
    float* h2     = h1 + (size_t)NN * FH;     // NN*FH

    hipMemsetAsync(deg, 0, NN * sizeof(int), stream);

    int eb = (NE + 255) / 256;
    k_hist   <<<eb, 256, 0, stream>>>(dst, deg);
    k_scan1  <<<NB1, 256, 0, stream>>>(deg, rowstart, btot);
    k_scan2  <<<1, 512, 0, stream>>>(btot, boff);
    k_scan3  <<<NB1, 256, 0, stream>>>(rowstart, boff, pos);
    k_scatter<<<eb, 256, 0, stream>>>(src, dst, pos, col);

    int ab = (NN * 64 + 255) / 256;  // one wave per node
    k_aggcsr<FI><<<ab, 256, 0, stream>>>(rowstart, col, x, aggbuf);
    k_trans<FI><<<NB1, 256, 0, stream>>>(x, aggbuf, Wl1, bl1, Wr1, g1, b1, m1, v1, h1);
    k_aggcsr<FH><<<ab, 256, 0, stream>>>(rowstart, col, h1, aggbuf);
    k_trans<FH><<<NB1, 256, 0, stream>>>(h1, aggbuf, Wl2, bl2, Wr2, g2, b2, m2, v2, h2);
    k_pool<<<NG, 256, 0, stream>>>(h2, bat, W1, bb1, W2, bb2, (float*)d_out);
}